// Round 9
// baseline (153.549 us; speedup 1.0000x reference)
//
#include <hip/hip_runtime.h>
#include <hip/hip_bf16.h>

#define NUM_USER 100000
#define K_NEIGH 32
#define DIM 64
#define HALF_USER 50000

typedef float floatx2 __attribute__((ext_vector_type(2)));
typedef float floatx4 __attribute__((ext_vector_type(4)));
typedef unsigned int uintx2 __attribute__((ext_vector_type(2)));

// Kernel 1: compress fp32 features -> packed bf16x2 table (RNE).
__global__ __launch_bounds__(256) void convert_bf16_kernel(
    const floatx2* __restrict__ feat2,   // 3.2M float2
    unsigned int*  __restrict__ table) { // 3.2M packed bf16x2
  int i = blockIdx.x * blockDim.x + threadIdx.x;
  if (i >= NUM_USER * DIM / 2) return;
  floatx2 f = feat2[i];
  unsigned int ux = __float_as_uint(f.x);
  unsigned int uy = __float_as_uint(f.y);
  unsigned int bx = (ux + 0x7fffu + ((ux >> 16) & 1u)) >> 16;
  unsigned int by = (uy + 0x7fffu + ((uy >> 16) & 1u)) >> 16;
  table[i] = bx | (by << 16);
}

// Kernel 2: gather+weighted-sum, TWO users per thread for forced MLP.
// 16 lanes per user-pair; lane owns dims {4*d4..4*d4+3} of both users.
// Each user's K-loop batched by 4 -> 8 structurally independent table
// loads in flight per thread. launch_bounds(256,4) frees the register
// allocator (R8's version was squeezed to 32 VGPR and serialized).
__global__ __launch_bounds__(256, 4) void gather_bf16_dual_kernel(
    const uintx2* __restrict__ table2,   // [NUM_USER][16] bf16x4 chunks
    const int*    __restrict__ graph,    // [NUM_USER][32]
    const float*  __restrict__ matrix,   // [NUM_USER][32]
    floatx4*      __restrict__ out4) {   // [NUM_USER][16] float4
  int t  = blockIdx.x * blockDim.x + threadIdx.x;
  int p  = t >> 4;
  int d4 = t & 15;
  if (p >= HALF_USER) return;
  int u0 = p;
  int u1 = p + HALF_USER;

  const int*   g0 = graph  + u0 * K_NEIGH;
  const float* w0 = matrix + u0 * K_NEIGH;
  const int*   g1 = graph  + u1 * K_NEIGH;
  const float* w1 = matrix + u1 * K_NEIGH;

  float a00 = 0.f, a01 = 0.f, a02 = 0.f, a03 = 0.f;
  float a10 = 0.f, a11 = 0.f, a12 = 0.f, a13 = 0.f;

#pragma unroll
  for (int kb = 0; kb < K_NEIGH; kb += 4) {
    int   i0[4], i1[4];
    float v0[4], v1[4];
#pragma unroll
    for (int j = 0; j < 4; ++j) {
      i0[j] = g0[kb + j];
      v0[j] = w0[kb + j];
      i1[j] = g1[kb + j];
      v1[j] = w1[kb + j];
    }
    uintx2 f0[4], f1[4];                 // 8 independent gathers in flight
#pragma unroll
    for (int j = 0; j < 4; ++j) {
      f0[j] = table2[i0[j] * 16 + d4];
      f1[j] = table2[i1[j] * 16 + d4];
    }
#pragma unroll
    for (int j = 0; j < 4; ++j) {
      a00 += v0[j] * __uint_as_float(f0[j].x << 16);
      a01 += v0[j] * __uint_as_float(f0[j].x & 0xffff0000u);
      a02 += v0[j] * __uint_as_float(f0[j].y << 16);
      a03 += v0[j] * __uint_as_float(f0[j].y & 0xffff0000u);
      a10 += v1[j] * __uint_as_float(f1[j].x << 16);
      a11 += v1[j] * __uint_as_float(f1[j].x & 0xffff0000u);
      a12 += v1[j] * __uint_as_float(f1[j].y << 16);
      a13 += v1[j] * __uint_as_float(f1[j].y & 0xffff0000u);
    }
  }
  floatx4 r0; r0.x = a00; r0.y = a01; r0.z = a02; r0.w = a03;
  floatx4 r1; r1.x = a10; r1.y = a11; r1.z = a12; r1.w = a13;
  out4[u0 * 16 + d4] = r0;               // 16B/lane coalesced stores
  out4[u1 * 16 + d4] = r1;
}

// Fallback (tiny ws): round-1 fp32 gather, known-good.
__global__ __launch_bounds__(256) void user_graph_gather_f32_kernel(
    const float* __restrict__ features,
    const int*   __restrict__ graph,
    const float* __restrict__ matrix,
    float*       __restrict__ out) {
  int t = blockIdx.x * blockDim.x + threadIdx.x;
  int u = t >> 6;
  int d = t & 63;
  if (u >= NUM_USER) return;
  const int*   g = graph  + (size_t)u * K_NEIGH;
  const float* w = matrix + (size_t)u * K_NEIGH;
  float acc = 0.f;
#pragma unroll
  for (int k = 0; k < K_NEIGH; ++k)
    acc += w[k] * features[(size_t)g[k] * DIM + d];
  out[(size_t)u * DIM + d] = acc;
}

extern "C" void kernel_launch(void* const* d_in, const int* in_sizes, int n_in,
                              void* d_out, int out_size, void* d_ws, size_t ws_size,
                              hipStream_t stream) {
  const float* features = (const float*)d_in[0];
  const int*   graph    = (const int*)d_in[1];
  const float* matrix   = (const float*)d_in[2];

  const size_t table_bytes = (size_t)NUM_USER * DIM * 2;  // 12.8 MB bf16

  if (ws_size >= table_bytes) {
    unsigned int* table = (unsigned int*)d_ws;
    const int n_pack = NUM_USER * DIM / 2;   // 3.2M
    convert_bf16_kernel<<<(n_pack + 255) / 256, 256, 0, stream>>>(
        (const floatx2*)features, table);
    const int total = HALF_USER * 16;        // 800k threads
    gather_bf16_dual_kernel<<<(total + 255) / 256, 256, 0, stream>>>(
        (const uintx2*)table, graph, matrix, (floatx4*)d_out);
  } else {
    const int total = NUM_USER * DIM;
    user_graph_gather_f32_kernel<<<(total + 255) / 256, 256, 0, stream>>>(
        features, graph, matrix, (float*)d_out);
  }
}